// Round 1
// baseline (111.878 us; speedup 1.0000x reference)
//
#include <hip/hip_runtime.h>

#define LOG2E 1.4426950408889634f

__device__ __forceinline__ float fast_exp2(float x) { return __builtin_amdgcn_exp2f(x); }
__device__ __forceinline__ float fast_rcp(float x)  { return __builtin_amdgcn_rcpf(x); }

// ---------------- prep: c[o] = 2*score_W[o], S0 = sum(score_W) + score_b ----------------
__global__ __launch_bounds__(512) void prep_kernel(const float* __restrict__ sW,
                                                   const float* __restrict__ sb,
                                                   float* __restrict__ cS) {
    const int t = threadIdx.x;
    float s = sW[t];
    cS[t] = 2.0f * s;
    __shared__ float red[512];
    red[t] = s;
    __syncthreads();
    for (int off = 256; off > 0; off >>= 1) {
        if (t < off) red[t] += red[t + off];
        __syncthreads();
    }
    if (t == 0) cS[512] = red[0] + sb[0];
}

// ---------------- stage 1: GEMM  P[m, n] = sum_h x[m,h] * W[n,h] ----------------
// m = b*256 + l  (row data at inputs[(l*8+b)*512]),  n in [0,1024): n<512 -> W1, else W2.
// Output written in panel layout: P[b][ti][o][ii]  (ti = l>>5, ii = l&31), pre-scaled by
// 2*log2(e), with attn_b folded into P1.
__global__ __launch_bounds__(256) void gemm_kernel(const float* __restrict__ inputs,
                                                   const float* __restrict__ attn_W,
                                                   const float* __restrict__ attn_b,
                                                   float* __restrict__ P1,
                                                   float* __restrict__ P2) {
    const int mt = blockIdx.x & 31;   // 32 m-tiles of 64
    const int nt = blockIdx.x >> 5;   // 16 n-tiles of 64
    __shared__ float smem[64 * 65];   // As[32][64] | Bs[32][64], reused as Csh[64][65]
    float* As = smem;                 // [k][m] stride 64
    float* Bs = smem + 2048;          // [k][n] stride 64

    const int t = threadIdx.x;
    const int tx = t & 15, ty = t >> 4;
    const int row = t >> 2;           // 0..63
    const int kq  = t & 3;            // 0..3

    // global row pointers
    const int m = mt * 64 + row;
    const int bb_ld = m >> 8, ll = m & 255;
    const float* arow = inputs + (ll * 8 + bb_ld) * 512;
    const int n = nt * 64 + row;
    const float* brow = attn_W + (n & 511) * 1024 + (n >> 9) * 512;

    float acc[4][4] = {};

    for (int k0 = 0; k0 < 512; k0 += 32) {
        float4 a0 = *(const float4*)(arow + k0 + kq * 4);
        float4 a1 = *(const float4*)(arow + k0 + kq * 4 + 16);
        float4 b0 = *(const float4*)(brow + k0 + kq * 4);
        float4 b1 = *(const float4*)(brow + k0 + kq * 4 + 16);
        __syncthreads();
        As[(kq * 4 + 0) * 64 + row] = a0.x;
        As[(kq * 4 + 1) * 64 + row] = a0.y;
        As[(kq * 4 + 2) * 64 + row] = a0.z;
        As[(kq * 4 + 3) * 64 + row] = a0.w;
        As[(kq * 4 + 16) * 64 + row] = a1.x;
        As[(kq * 4 + 17) * 64 + row] = a1.y;
        As[(kq * 4 + 18) * 64 + row] = a1.z;
        As[(kq * 4 + 19) * 64 + row] = a1.w;
        Bs[(kq * 4 + 0) * 64 + row] = b0.x;
        Bs[(kq * 4 + 1) * 64 + row] = b0.y;
        Bs[(kq * 4 + 2) * 64 + row] = b0.z;
        Bs[(kq * 4 + 3) * 64 + row] = b0.w;
        Bs[(kq * 4 + 16) * 64 + row] = b1.x;
        Bs[(kq * 4 + 17) * 64 + row] = b1.y;
        Bs[(kq * 4 + 18) * 64 + row] = b1.z;
        Bs[(kq * 4 + 19) * 64 + row] = b1.w;
        __syncthreads();
#pragma unroll 8
        for (int k = 0; k < 32; ++k) {
            float4 av = *(const float4*)&As[k * 64 + ty * 4];
            float4 bv = *(const float4*)&Bs[k * 64 + tx * 4];
            acc[0][0] += av.x * bv.x; acc[0][1] += av.x * bv.y;
            acc[0][2] += av.x * bv.z; acc[0][3] += av.x * bv.w;
            acc[1][0] += av.y * bv.x; acc[1][1] += av.y * bv.y;
            acc[1][2] += av.y * bv.z; acc[1][3] += av.y * bv.w;
            acc[2][0] += av.z * bv.x; acc[2][1] += av.z * bv.y;
            acc[2][2] += av.z * bv.z; acc[2][3] += av.z * bv.w;
            acc[3][0] += av.w * bv.x; acc[3][1] += av.w * bv.y;
            acc[3][2] += av.w * bv.z; acc[3][3] += av.w * bv.w;
        }
    }

    // epilogue: stage C tile in LDS (stride 65), then coalesced panel writes
    __syncthreads();
#pragma unroll
    for (int q = 0; q < 4; ++q)
#pragma unroll
        for (int r = 0; r < 4; ++r)
            smem[(ty * 4 + q) * 65 + tx * 4 + r] = acc[q][r];
    __syncthreads();

    const float scale = 2.0f * LOG2E;
    const int bb = mt >> 2;
    const int tibase = (mt & 3) * 2;
#pragma unroll
    for (int it = 0; it < 16; ++it) {
        int f = it * 256 + t;
        int ii = f & 31;
        int half = (f >> 5) & 1;
        int ol = f >> 6;                 // 0..63
        float v = smem[(half * 32 + ii) * 65 + ol];
        int ngl = nt * 64 + ol;
        int o = ngl & 511;
        long idx = (((long)(bb * 8 + tibase + half)) * 512 + o) * 32 + ii;
        if (ngl < 512) P1[idx] = scale * (v + attn_b[o]);
        else           P2[idx] = scale * v;
    }
}

// ---------------- stage 2: energies E[b,i,j] = S0 - sum_o c[o] * rcp(1 + exp2(u)) ----------------
// u = P1[b,i,o] + P2[b,j,o] (already scaled by 2*log2e, bias folded).
__global__ __launch_bounds__(256) void energy_kernel(const float* __restrict__ P1,
                                                     const float* __restrict__ P2,
                                                     const float* __restrict__ cS,
                                                     float* __restrict__ E) {
    const int bid = blockIdx.x;       // 512 = 8 b * 8 ti * 8 tj
    const int b  = bid >> 6;
    const int ti = (bid >> 3) & 7;
    const int tj = bid & 7;
    __shared__ float p1s[64 * 32];    // [hh][ii]
    __shared__ float p2s[64 * 32];    // [hh][jj]
    __shared__ float csh[512];

    const int t = threadIdx.x;
    const int tx = t & 15, ty = t >> 4;

    csh[t] = cS[t];
    csh[256 + t] = cS[256 + t];

    const float* p1base = P1 + (long)(b * 8 + ti) * 512 * 32;
    const float* p2base = P2 + (long)(b * 8 + tj) * 512 * 32;

    float acc00 = 0.f, acc01 = 0.f, acc10 = 0.f, acc11 = 0.f;

    for (int h0 = 0; h0 < 512; h0 += 64) {
        __syncthreads();
        const float4* s1 = (const float4*)(p1base + h0 * 32);
        const float4* s2 = (const float4*)(p2base + h0 * 32);
        float4* d1 = (float4*)p1s;
        float4* d2 = (float4*)p2s;
        d1[t] = s1[t];  d1[256 + t] = s1[256 + t];
        d2[t] = s2[t];  d2[256 + t] = s2[256 + t];
        __syncthreads();
#pragma unroll 8
        for (int hh = 0; hh < 64; ++hh) {
            float c = csh[h0 + hh];
            float2 a  = *(const float2*)&p1s[hh * 32 + ty * 2];
            float2 bj = *(const float2*)&p2s[hh * 32 + tx * 2];
            acc00 += c * fast_rcp(1.0f + fast_exp2(a.x + bj.x));
            acc01 += c * fast_rcp(1.0f + fast_exp2(a.x + bj.y));
            acc10 += c * fast_rcp(1.0f + fast_exp2(a.y + bj.x));
            acc11 += c * fast_rcp(1.0f + fast_exp2(a.y + bj.y));
        }
    }

    const float S0 = cS[512];
    float* Eb = E + (long)b * 65536 + (ti * 32) * 256 + tj * 32;
    float2 r0 = make_float2(S0 - acc00, S0 - acc01);
    float2 r1 = make_float2(S0 - acc10, S0 - acc11);
    *(float2*)&Eb[(ty * 2 + 0) * 256 + tx * 2] = r0;
    *(float2*)&Eb[(ty * 2 + 1) * 256 + tx * 2] = r1;
}

// ---------------- stage 3: softmax over i (axis=1) ----------------
__global__ __launch_bounds__(256) void softmax_kernel(const float* __restrict__ E,
                                                      float* __restrict__ out) {
    const int b = blockIdx.x >> 3;
    const int jt = blockIdx.x & 7;
    const int t = threadIdx.x;
    const int jx = t & 31;
    const int iy = t >> 5;              // 0..7
    const float* Eb = E + (long)b * 65536 + jt * 32 + jx;

    float m = -3.0e38f;
#pragma unroll
    for (int k = 0; k < 32; ++k) m = fmaxf(m, Eb[(iy + k * 8) * 256]);

    __shared__ float red[256];
    red[t] = m;
    __syncthreads();
    if (t < 128) red[t] = fmaxf(red[t], red[t + 128]);
    __syncthreads();
    if (t < 64) red[t] = fmaxf(red[t], red[t + 64]);
    __syncthreads();
    if (t < 32) red[t] = fmaxf(red[t], red[t + 32]);
    __syncthreads();
    m = red[jx];
    __syncthreads();

    float s = 0.f;
#pragma unroll
    for (int k = 0; k < 32; ++k) s += fast_exp2((Eb[(iy + k * 8) * 256] - m) * LOG2E);
    red[t] = s;
    __syncthreads();
    if (t < 128) red[t] += red[t + 128];
    __syncthreads();
    if (t < 64) red[t] += red[t + 64];
    __syncthreads();
    if (t < 32) red[t] += red[t + 32];
    __syncthreads();
    float inv = fast_rcp(red[jx]);

    float* ob = out + (long)b * 65536 + jt * 32 + jx;
#pragma unroll
    for (int k = 0; k < 32; ++k) {
        int i = iy + k * 8;
        ob[i * 256] = fast_exp2((Eb[i * 256] - m) * LOG2E) * inv;
    }
}

extern "C" void kernel_launch(void* const* d_in, const int* in_sizes, int n_in,
                              void* d_out, int out_size, void* d_ws, size_t ws_size,
                              hipStream_t stream) {
    const float* inputs  = (const float*)d_in[0];  // (256, 8, 512)
    const float* attn_W  = (const float*)d_in[1];  // (512, 1024)
    const float* attn_b  = (const float*)d_in[2];  // (512,)
    const float* score_W = (const float*)d_in[3];  // (1, 512)
    const float* score_b = (const float*)d_in[4];  // (1,)
    float* out = (float*)d_out;                    // (8, 256, 256)

    float* ws = (float*)d_ws;
    float* P1 = ws;                                // 2048*512 floats (panel layout)
    float* P2 = ws + (1 << 20);                    // 2048*512 floats
    float* E  = ws + (2 << 20);                    // 8*256*256 floats
    float* cS = ws + (2 << 20) + 524288;           // c[512] + S0

    prep_kernel<<<1, 512, 0, stream>>>(score_W, score_b, cS);
    gemm_kernel<<<512, 256, 0, stream>>>(inputs, attn_W, attn_b, P1, P2);
    energy_kernel<<<512, 256, 0, stream>>>(P1, P2, cS, E);
    softmax_kernel<<<64, 256, 0, stream>>>(E, out);
}

// Round 2
// 80.711 us; speedup vs baseline: 1.3862x; 1.3862x over previous
//
#include <hip/hip_runtime.h>

#define LOG2E 1.4426950408889634f
#define SCALE (2.0f * LOG2E)

__device__ __forceinline__ float fast_exp2(float x) { return __builtin_amdgcn_exp2f(x); }
__device__ __forceinline__ float fast_rcp(float x)  { return __builtin_amdgcn_rcpf(x); }

// ---------------- stage 1: GEMM  P[m, n] = sum_h x[m,h] * W[n,h] ----------------
// m = b*256 + l  (row data at inputs[(l*8+b)*512]),  n in [0,1024): n<512 -> W1, else W2.
// Epilogue stores EXPONENTIALS in panel layout: E1[b][ti][o][ii] = exp2(SCALE*(p1+bias)),
// E2[b][ti][o][ii] = exp2(SCALE*p2)  (ti = l>>5, ii = l&31), so the energy kernel needs
// no exp2: e^{2z} = E1 * E2.
__global__ __launch_bounds__(256) void gemm_kernel(const float* __restrict__ inputs,
                                                   const float* __restrict__ attn_W,
                                                   const float* __restrict__ attn_b,
                                                   float* __restrict__ E1,
                                                   float* __restrict__ E2) {
    const int mt = blockIdx.x & 31;   // 32 m-tiles of 64
    const int nt = blockIdx.x >> 5;   // 16 n-tiles of 64
    __shared__ float smem[64 * 65];   // As[32][64] | Bs[32][64], reused as Csh[64][65]
    float* As = smem;                 // [k][m] stride 64
    float* Bs = smem + 2048;          // [k][n] stride 64

    const int t = threadIdx.x;
    const int tx = t & 15, ty = t >> 4;
    const int row = t >> 2;           // 0..63
    const int kq  = t & 3;            // 0..3

    const int m = mt * 64 + row;
    const int bb_ld = m >> 8, ll = m & 255;
    const float* arow = inputs + (ll * 8 + bb_ld) * 512;
    const int n = nt * 64 + row;
    const float* brow = attn_W + (n & 511) * 1024 + (n >> 9) * 512;

    float acc[4][4] = {};

    for (int k0 = 0; k0 < 512; k0 += 32) {
        float4 a0 = *(const float4*)(arow + k0 + kq * 4);
        float4 a1 = *(const float4*)(arow + k0 + kq * 4 + 16);
        float4 b0 = *(const float4*)(brow + k0 + kq * 4);
        float4 b1 = *(const float4*)(brow + k0 + kq * 4 + 16);
        __syncthreads();
        As[(kq * 4 + 0) * 64 + row] = a0.x;
        As[(kq * 4 + 1) * 64 + row] = a0.y;
        As[(kq * 4 + 2) * 64 + row] = a0.z;
        As[(kq * 4 + 3) * 64 + row] = a0.w;
        As[(kq * 4 + 16) * 64 + row] = a1.x;
        As[(kq * 4 + 17) * 64 + row] = a1.y;
        As[(kq * 4 + 18) * 64 + row] = a1.z;
        As[(kq * 4 + 19) * 64 + row] = a1.w;
        Bs[(kq * 4 + 0) * 64 + row] = b0.x;
        Bs[(kq * 4 + 1) * 64 + row] = b0.y;
        Bs[(kq * 4 + 2) * 64 + row] = b0.z;
        Bs[(kq * 4 + 3) * 64 + row] = b0.w;
        Bs[(kq * 4 + 16) * 64 + row] = b1.x;
        Bs[(kq * 4 + 17) * 64 + row] = b1.y;
        Bs[(kq * 4 + 18) * 64 + row] = b1.z;
        Bs[(kq * 4 + 19) * 64 + row] = b1.w;
        __syncthreads();
#pragma unroll 8
        for (int k = 0; k < 32; ++k) {
            float4 av = *(const float4*)&As[k * 64 + ty * 4];
            float4 bv = *(const float4*)&Bs[k * 64 + tx * 4];
            acc[0][0] += av.x * bv.x; acc[0][1] += av.x * bv.y;
            acc[0][2] += av.x * bv.z; acc[0][3] += av.x * bv.w;
            acc[1][0] += av.y * bv.x; acc[1][1] += av.y * bv.y;
            acc[1][2] += av.y * bv.z; acc[1][3] += av.y * bv.w;
            acc[2][0] += av.z * bv.x; acc[2][1] += av.z * bv.y;
            acc[2][2] += av.z * bv.z; acc[2][3] += av.z * bv.w;
            acc[3][0] += av.w * bv.x; acc[3][1] += av.w * bv.y;
            acc[3][2] += av.w * bv.z; acc[3][3] += av.w * bv.w;
        }
    }

    __syncthreads();
#pragma unroll
    for (int q = 0; q < 4; ++q)
#pragma unroll
        for (int r = 0; r < 4; ++r)
            smem[(ty * 4 + q) * 65 + tx * 4 + r] = acc[q][r];
    __syncthreads();

    const int bb = mt >> 2;
    const int tibase = (mt & 3) * 2;
#pragma unroll
    for (int it = 0; it < 16; ++it) {
        int f = it * 256 + t;
        int ii = f & 31;
        int half = (f >> 5) & 1;
        int ol = f >> 6;                 // 0..63
        float v = smem[(half * 32 + ii) * 65 + ol];
        int ngl = nt * 64 + ol;
        int o = ngl & 511;
        long idx = (((long)(bb * 8 + tibase + half)) * 512 + o) * 32 + ii;
        if (ngl < 512) E1[idx] = fast_exp2(SCALE * (v + attn_b[o]));
        else           E2[idx] = fast_exp2(SCALE * v);
    }
}

// ---------------- stage 2: partial energies ----------------
// EP[s][b][i][j] = sum_{o in chunk s} c[o] * rcp(1 + E1[b,i,o]*E2[b,j,o]),  c[o]=2*score_W[o]
// (energies = const - sum_s EP[s]; the const cancels in softmax)
__global__ __launch_bounds__(256) void energy_kernel(const float* __restrict__ E1,
                                                     const float* __restrict__ E2,
                                                     const float* __restrict__ sW,
                                                     float* __restrict__ EP) {
    const int bid = blockIdx.x;       // 2048 = 8 b * 8 ti * 8 tj * 4 s
    const int s  = bid & 3;
    const int tj = (bid >> 2) & 7;
    const int ti = (bid >> 5) & 7;
    const int b  = bid >> 8;
    __shared__ float p1s[64 * 32];    // [hh][ii]
    __shared__ float p2s[64 * 32];    // [hh][jj]
    __shared__ float csh[128];

    const int t = threadIdx.x;
    const int tx = t & 15, ty = t >> 4;

    if (t < 128) csh[t] = 2.0f * sW[s * 128 + t];

    const float* p1base = E1 + ((long)(b * 8 + ti) * 512 + s * 128) * 32;
    const float* p2base = E2 + ((long)(b * 8 + tj) * 512 + s * 128) * 32;

    float acc00 = 0.f, acc01 = 0.f, acc10 = 0.f, acc11 = 0.f;

    for (int c0 = 0; c0 < 128; c0 += 64) {
        __syncthreads();
        const float4* s1 = (const float4*)(p1base + c0 * 32);
        const float4* s2 = (const float4*)(p2base + c0 * 32);
        float4* d1 = (float4*)p1s;
        float4* d2 = (float4*)p2s;
        d1[t] = s1[t];  d1[256 + t] = s1[256 + t];
        d2[t] = s2[t];  d2[256 + t] = s2[256 + t];
        __syncthreads();
#pragma unroll 8
        for (int hh = 0; hh < 64; ++hh) {
            float c = csh[c0 + hh];
            float2 a  = *(const float2*)&p1s[hh * 32 + ty * 2];
            float2 bj = *(const float2*)&p2s[hh * 32 + tx * 2];
            acc00 = fmaf(c, fast_rcp(fmaf(a.x, bj.x, 1.0f)), acc00);
            acc01 = fmaf(c, fast_rcp(fmaf(a.x, bj.y, 1.0f)), acc01);
            acc10 = fmaf(c, fast_rcp(fmaf(a.y, bj.x, 1.0f)), acc10);
            acc11 = fmaf(c, fast_rcp(fmaf(a.y, bj.y, 1.0f)), acc11);
        }
    }

    float* Eb = EP + (long)s * 524288 + (long)b * 65536 + (ti * 32) * 256 + tj * 32;
    float2 r0 = make_float2(acc00, acc01);
    float2 r1 = make_float2(acc10, acc11);
    *(float2*)&Eb[(ty * 2 + 0) * 256 + tx * 2] = r0;
    *(float2*)&Eb[(ty * 2 + 1) * 256 + tx * 2] = r1;
}

// ---------------- stage 3: combine partials + softmax over i (axis=1) ----------------
// logits v[b,i,j] = -(EP0+EP1+EP2+EP3)  (constant shift dropped — softmax invariant)
__global__ __launch_bounds__(256) void softmax_kernel(const float* __restrict__ P0,
                                                      const float* __restrict__ P1,
                                                      const float* __restrict__ P2,
                                                      const float* __restrict__ P3,
                                                      float* __restrict__ out) {
    const int b  = blockIdx.x >> 4;
    const int jt = blockIdx.x & 15;     // 16-col tiles
    const int t  = threadIdx.x;
    const int jx = t & 15;
    const int iy = t >> 4;              // 0..15
    const long base = (long)b * 65536 + jt * 16 + jx;

    float v[16];
#pragma unroll
    for (int k = 0; k < 16; ++k) {
        long idx = base + (long)(iy + k * 16) * 256;
        v[k] = -(P0[idx] + P1[idx] + P2[idx] + P3[idx]);
    }

    float m = v[0];
#pragma unroll
    for (int k = 1; k < 16; ++k) m = fmaxf(m, v[k]);

    __shared__ float red[256];
    red[t] = m;
    __syncthreads();
    if (t < 128) red[t] = fmaxf(red[t], red[t + 128]);
    __syncthreads();
    if (t < 64) red[t] = fmaxf(red[t], red[t + 64]);
    __syncthreads();
    if (t < 32) red[t] = fmaxf(red[t], red[t + 32]);
    __syncthreads();
    if (t < 16) red[t] = fmaxf(red[t], red[t + 16]);
    __syncthreads();
    m = red[jx];
    __syncthreads();

    float ssum = 0.f;
#pragma unroll
    for (int k = 0; k < 16; ++k) {
        v[k] = fast_exp2((v[k] - m) * LOG2E);
        ssum += v[k];
    }
    red[t] = ssum;
    __syncthreads();
    if (t < 128) red[t] += red[t + 128];
    __syncthreads();
    if (t < 64) red[t] += red[t + 64];
    __syncthreads();
    if (t < 32) red[t] += red[t + 32];
    __syncthreads();
    if (t < 16) red[t] += red[t + 16];
    __syncthreads();
    float inv = fast_rcp(red[jx]);

#pragma unroll
    for (int k = 0; k < 16; ++k) {
        long idx = base + (long)(iy + k * 16) * 256;
        out[idx] = v[k] * inv;
    }
}

extern "C" void kernel_launch(void* const* d_in, const int* in_sizes, int n_in,
                              void* d_out, int out_size, void* d_ws, size_t ws_size,
                              hipStream_t stream) {
    const float* inputs  = (const float*)d_in[0];  // (256, 8, 512)
    const float* attn_W  = (const float*)d_in[1];  // (512, 1024)
    const float* attn_b  = (const float*)d_in[2];  // (512,)
    const float* score_W = (const float*)d_in[3];  // (1, 512)
    float* out = (float*)d_out;                    // (8, 256, 256)

    float* ws = (float*)d_ws;
    float* E1 = ws;                                // 2048*512 floats (exp panel)
    float* E2 = ws + (1 << 20);                    // 2048*512 floats
    float* EP = ws + (2 << 20);                    // 4 * 8*256*256 floats (partials)

    gemm_kernel<<<512, 256, 0, stream>>>(inputs, attn_W, attn_b, E1, E2);
    energy_kernel<<<2048, 256, 0, stream>>>(E1, E2, score_W, EP);
    softmax_kernel<<<128, 256, 0, stream>>>(EP, EP + 524288, EP + 2 * 524288,
                                            EP + 3 * 524288, out);
}

// Round 3
// 76.318 us; speedup vs baseline: 1.4660x; 1.0576x over previous
//
#include <hip/hip_runtime.h>

#define LOG2E 1.4426950408889634f
#define SCALE (2.0f * LOG2E)

__device__ __forceinline__ float fast_exp2(float x) { return __builtin_amdgcn_exp2f(x); }
__device__ __forceinline__ float fast_rcp(float x)  { return __builtin_amdgcn_rcpf(x); }

// ---------------- stage 1: GEMM  P[m, n] = sum_h x[m,h] * W[n,h] ----------------
// m = b*256 + l  (row data at inputs[(l*8+b)*512]),  n in [0,1024): n<512 -> W1, else W2.
// Double-buffered BK=32, one barrier per K-tile, global->reg prefetch.
// Epilogue stores EXPONENTIALS in panel layout: E1[b][ti][o][ii] = exp2(SCALE*(p1+bias)),
// E2[b][ti][o][ii] = exp2(SCALE*p2)  (ti = l>>5, ii = l&31).
__global__ __launch_bounds__(256, 2) void gemm_kernel(const float* __restrict__ inputs,
                                                      const float* __restrict__ attn_W,
                                                      const float* __restrict__ attn_b,
                                                      float* __restrict__ E1,
                                                      float* __restrict__ E2) {
    const int mt = blockIdx.x & 31;   // 32 m-tiles of 64
    const int nt = blockIdx.x >> 5;   // 16 n-tiles of 64
    __shared__ float smem[8192];      // As[2][32][64] | Bs[2][32][64]; epilogue Csh[64][65]
    float* const As = smem;           // [buf][k][m]
    float* const Bs = smem + 4096;    // [buf][k][n]

    const int t = threadIdx.x;
    const int tx = t & 15, ty = t >> 4;
    const int row = t >> 2;           // 0..63
    const int kq  = t & 3;            // 0..3

    const int m = mt * 64 + row;
    const int bb_ld = m >> 8, ll = m & 255;
    const float* arow = inputs + (ll * 8 + bb_ld) * 512;
    const int n = nt * 64 + row;
    const float* brow = attn_W + (n & 511) * 1024 + (n >> 9) * 512;

    float acc[4][4] = {};
    float4 a0, a1, b0, b1;

    // prologue: load tile 0, stage into buf 0
    a0 = *(const float4*)(arow + kq * 4);
    a1 = *(const float4*)(arow + kq * 4 + 16);
    b0 = *(const float4*)(brow + kq * 4);
    b1 = *(const float4*)(brow + kq * 4 + 16);
#pragma unroll
    for (int j = 0; j < 4; ++j) {
        As[(kq * 4 + j) * 64 + row]      = ((const float*)&a0)[j];
        As[(kq * 4 + 16 + j) * 64 + row] = ((const float*)&a1)[j];
        Bs[(kq * 4 + j) * 64 + row]      = ((const float*)&b0)[j];
        Bs[(kq * 4 + 16 + j) * 64 + row] = ((const float*)&b1)[j];
    }
    __syncthreads();

    for (int tile = 0; tile < 16; ++tile) {
        const int cur = tile & 1;
        // prefetch next tile (global -> regs); drains under the compute below
        if (tile < 15) {
            const int k0 = (tile + 1) * 32;
            a0 = *(const float4*)(arow + k0 + kq * 4);
            a1 = *(const float4*)(arow + k0 + kq * 4 + 16);
            b0 = *(const float4*)(brow + k0 + kq * 4);
            b1 = *(const float4*)(brow + k0 + kq * 4 + 16);
        }
        const float* Ac = As + cur * 2048;
        const float* Bc = Bs + cur * 2048;
#pragma unroll 8
        for (int k = 0; k < 32; ++k) {
            float4 av = *(const float4*)&Ac[k * 64 + ty * 4];
            float4 bv = *(const float4*)&Bc[k * 64 + tx * 4];
            acc[0][0] = fmaf(av.x, bv.x, acc[0][0]); acc[0][1] = fmaf(av.x, bv.y, acc[0][1]);
            acc[0][2] = fmaf(av.x, bv.z, acc[0][2]); acc[0][3] = fmaf(av.x, bv.w, acc[0][3]);
            acc[1][0] = fmaf(av.y, bv.x, acc[1][0]); acc[1][1] = fmaf(av.y, bv.y, acc[1][1]);
            acc[1][2] = fmaf(av.y, bv.z, acc[1][2]); acc[1][3] = fmaf(av.y, bv.w, acc[1][3]);
            acc[2][0] = fmaf(av.z, bv.x, acc[2][0]); acc[2][1] = fmaf(av.z, bv.y, acc[2][1]);
            acc[2][2] = fmaf(av.z, bv.z, acc[2][2]); acc[2][3] = fmaf(av.z, bv.w, acc[2][3]);
            acc[3][0] = fmaf(av.w, bv.x, acc[3][0]); acc[3][1] = fmaf(av.w, bv.y, acc[3][1]);
            acc[3][2] = fmaf(av.w, bv.z, acc[3][2]); acc[3][3] = fmaf(av.w, bv.w, acc[3][3]);
        }
        // stage next tile into the other buffer (safe: last read before previous barrier)
        if (tile < 15) {
            float* An = As + (cur ^ 1) * 2048;
            float* Bn = Bs + (cur ^ 1) * 2048;
#pragma unroll
            for (int j = 0; j < 4; ++j) {
                An[(kq * 4 + j) * 64 + row]      = ((const float*)&a0)[j];
                An[(kq * 4 + 16 + j) * 64 + row] = ((const float*)&a1)[j];
                Bn[(kq * 4 + j) * 64 + row]      = ((const float*)&b0)[j];
                Bn[(kq * 4 + 16 + j) * 64 + row] = ((const float*)&b1)[j];
            }
        }
        __syncthreads();
    }

    // epilogue: stage C tile in LDS (stride 65), then coalesced panel writes with exp2
#pragma unroll
    for (int q = 0; q < 4; ++q)
#pragma unroll
        for (int r = 0; r < 4; ++r)
            smem[(ty * 4 + q) * 65 + tx * 4 + r] = acc[q][r];
    __syncthreads();

    const int bb = mt >> 2;
    const int tibase = (mt & 3) * 2;
#pragma unroll
    for (int it = 0; it < 16; ++it) {
        int f = it * 256 + t;
        int ii = f & 31;
        int half = (f >> 5) & 1;
        int ol = f >> 6;                 // 0..63
        float v = smem[(half * 32 + ii) * 65 + ol];
        int ngl = nt * 64 + ol;
        int o = ngl & 511;
        long idx = (((long)(bb * 8 + tibase + half)) * 512 + o) * 32 + ii;
        if (ngl < 512) E1[idx] = fast_exp2(SCALE * (v + attn_b[o]));
        else           E2[idx] = fast_exp2(SCALE * v);
    }
}

// ---------------- stage 2: partial energies ----------------
// EP[s][b][i][j] = sum_{o in chunk s} c[o] * rcp(1 + E1[b,i,o]*E2[b,j,o]),  c[o]=2*score_W[o]
__global__ __launch_bounds__(256) void energy_kernel(const float* __restrict__ E1,
                                                     const float* __restrict__ E2,
                                                     const float* __restrict__ sW,
                                                     float* __restrict__ EP) {
    const int bid = blockIdx.x;       // 2048 = 8 b * 8 ti * 8 tj * 4 s
    const int s  = bid & 3;
    const int tj = (bid >> 2) & 7;
    const int ti = (bid >> 5) & 7;
    const int b  = bid >> 8;
    __shared__ float p1s[64 * 32];    // [hh][ii]
    __shared__ float p2s[64 * 32];    // [hh][jj]
    __shared__ float csh[128];

    const int t = threadIdx.x;
    const int tx = t & 15, ty = t >> 4;

    if (t < 128) csh[t] = 2.0f * sW[s * 128 + t];

    const float* p1base = E1 + ((long)(b * 8 + ti) * 512 + s * 128) * 32;
    const float* p2base = E2 + ((long)(b * 8 + tj) * 512 + s * 128) * 32;

    float acc00 = 0.f, acc01 = 0.f, acc10 = 0.f, acc11 = 0.f;

    for (int c0 = 0; c0 < 128; c0 += 64) {
        __syncthreads();
        const float4* s1 = (const float4*)(p1base + c0 * 32);
        const float4* s2 = (const float4*)(p2base + c0 * 32);
        float4* d1 = (float4*)p1s;
        float4* d2 = (float4*)p2s;
        d1[t] = s1[t];  d1[256 + t] = s1[256 + t];
        d2[t] = s2[t];  d2[256 + t] = s2[256 + t];
        __syncthreads();
#pragma unroll 8
        for (int hh = 0; hh < 64; ++hh) {
            float c = csh[c0 + hh];
            float2 a  = *(const float2*)&p1s[hh * 32 + ty * 2];
            float2 bj = *(const float2*)&p2s[hh * 32 + tx * 2];
            acc00 = fmaf(c, fast_rcp(fmaf(a.x, bj.x, 1.0f)), acc00);
            acc01 = fmaf(c, fast_rcp(fmaf(a.x, bj.y, 1.0f)), acc01);
            acc10 = fmaf(c, fast_rcp(fmaf(a.y, bj.x, 1.0f)), acc10);
            acc11 = fmaf(c, fast_rcp(fmaf(a.y, bj.y, 1.0f)), acc11);
        }
    }

    float* Eb = EP + (long)s * 524288 + (long)b * 65536 + (ti * 32) * 256 + tj * 32;
    *(float2*)&Eb[(ty * 2 + 0) * 256 + tx * 2] = make_float2(acc00, acc01);
    *(float2*)&Eb[(ty * 2 + 1) * 256 + tx * 2] = make_float2(acc10, acc11);
}

// ---------------- stage 3: combine partials + softmax over i (axis=1) ----------------
__global__ __launch_bounds__(256) void softmax_kernel(const float* __restrict__ P0,
                                                      const float* __restrict__ P1,
                                                      const float* __restrict__ P2,
                                                      const float* __restrict__ P3,
                                                      float* __restrict__ out) {
    const int b  = blockIdx.x >> 4;
    const int jt = blockIdx.x & 15;     // 16-col tiles
    const int t  = threadIdx.x;
    const int jx = t & 15;
    const int iy = t >> 4;              // 0..15
    const long base = (long)b * 65536 + jt * 16 + jx;

    float v[16];
#pragma unroll
    for (int k = 0; k < 16; ++k) {
        long idx = base + (long)(iy + k * 16) * 256;
        v[k] = -(P0[idx] + P1[idx] + P2[idx] + P3[idx]);
    }

    float m = v[0];
#pragma unroll
    for (int k = 1; k < 16; ++k) m = fmaxf(m, v[k]);

    __shared__ float red[256];
    red[t] = m;
    __syncthreads();
    if (t < 128) red[t] = fmaxf(red[t], red[t + 128]);
    __syncthreads();
    if (t < 64) red[t] = fmaxf(red[t], red[t + 64]);
    __syncthreads();
    if (t < 32) red[t] = fmaxf(red[t], red[t + 32]);
    __syncthreads();
    if (t < 16) red[t] = fmaxf(red[t], red[t + 16]);
    __syncthreads();
    m = red[jx];
    __syncthreads();

    float ssum = 0.f;
#pragma unroll
    for (int k = 0; k < 16; ++k) {
        v[k] = fast_exp2((v[k] - m) * LOG2E);
        ssum += v[k];
    }
    red[t] = ssum;
    __syncthreads();
    if (t < 128) red[t] += red[t + 128];
    __syncthreads();
    if (t < 64) red[t] += red[t + 64];
    __syncthreads();
    if (t < 32) red[t] += red[t + 32];
    __syncthreads();
    if (t < 16) red[t] += red[t + 16];
    __syncthreads();
    float inv = fast_rcp(red[jx]);

#pragma unroll
    for (int k = 0; k < 16; ++k) {
        long idx = base + (long)(iy + k * 16) * 256;
        out[idx] = v[k] * inv;
    }
}

extern "C" void kernel_launch(void* const* d_in, const int* in_sizes, int n_in,
                              void* d_out, int out_size, void* d_ws, size_t ws_size,
                              hipStream_t stream) {
    const float* inputs  = (const float*)d_in[0];  // (256, 8, 512)
    const float* attn_W  = (const float*)d_in[1];  // (512, 1024)
    const float* attn_b  = (const float*)d_in[2];  // (512,)
    const float* score_W = (const float*)d_in[3];  // (1, 512)
    float* out = (float*)d_out;                    // (8, 256, 256)

    float* ws = (float*)d_ws;
    float* E1 = ws;                                // 2048*512 floats (exp panel)
    float* E2 = ws + (1 << 20);                    // 2048*512 floats
    float* EP = ws + (2 << 20);                    // 4 * 8*256*256 floats (partials)

    gemm_kernel<<<512, 256, 0, stream>>>(inputs, attn_W, attn_b, E1, E2);
    energy_kernel<<<2048, 256, 0, stream>>>(E1, E2, score_W, EP);
    softmax_kernel<<<128, 256, 0, stream>>>(EP, EP + 524288, EP + 2 * 524288,
                                            EP + 3 * 524288, out);
}

// Round 4
// 64.229 us; speedup vs baseline: 1.7419x; 1.1882x over previous
//
#include <hip/hip_runtime.h>

#define LOG2E 1.4426950408889634f
#define SCALE (2.0f * LOG2E)

__device__ __forceinline__ float fast_exp2(float x) { return __builtin_amdgcn_exp2f(x); }
__device__ __forceinline__ float fast_rcp(float x)  { return __builtin_amdgcn_rcpf(x); }

typedef __attribute__((ext_vector_type(8))) short bf16x8;
typedef __attribute__((ext_vector_type(4))) float f32x4;

// ---------------- stage 0: pack A/B into bf16 hi/lo MFMA fragment panels ----------------
// Logical GEMM: C[m,n] = sum_{kp=0}^{1535} A[m,kp]*B[n,kp]
//   kp segment 0: x_hi * w_hi ; 1: x_lo * w_hi ; 2: x_hi * w_lo   (lo*lo dropped, ~1e-5 rel)
// Panel layout (ushort): [tileblk64][kt(24)][ks(2)][frag(4)][lane(64)][j(8)]
//   A element: m = tb*64 + frag*16 + (l&15), kphys = kt*64+ks*32+(l>>4)*8+j
//   (matches v_mfma_f32_16x16x32_bf16 operand layout: row=l&15, k=(l>>4)*8+j)
__global__ __launch_bounds__(256) void pack_kernel(const float* __restrict__ inputs,
                                                   const float* __restrict__ attn_W,
                                                   ushort* __restrict__ Ap,
                                                   ushort* __restrict__ Bp) {
    int tid = blockIdx.x * 256 + threadIdx.x;
    const bool isA = tid < 393216;
    int f = isA ? tid : tid - 393216;
    int l  = f & 63;
    int fr = (f >> 6) & 3;
    int ks = (f >> 8) & 1;
    int rem = f >> 9;
    int kt = rem % 24, tb = rem / 24;
    int kp = kt * 64 + ks * 32 + (l >> 4) * 8;
    int seg = kp >> 9, k = kp & 511;
    const float* src;
    bool useLo;
    if (isA) {
        int m = tb * 64 + fr * 16 + (l & 15);            // m = b*256 + l_seq
        src = inputs + ((m & 255) * 8 + (m >> 8)) * 512 + k;
        useLo = (seg == 1);
    } else {
        int n = tb * 64 + fr * 16 + (l & 15);            // n<512: W1 col, else W2
        src = attn_W + (n & 511) * 1024 + (n >> 9) * 512 + k;
        useLo = (seg == 2);
    }
    float4 v0 = *(const float4*)src;
    float4 v1 = *(const float4*)(src + 4);
    float vv[8] = {v0.x, v0.y, v0.z, v0.w, v1.x, v1.y, v1.z, v1.w};
    ushort o[8];
#pragma unroll
    for (int j = 0; j < 8; ++j) {
        unsigned u = __float_as_uint(vv[j]);
        unsigned hi = (u + 0x7FFF + ((u >> 16) & 1)) >> 16;   // RN bf16
        if (useLo) {
            float lo = vv[j] - __uint_as_float(hi << 16);
            unsigned ul = __float_as_uint(lo);
            o[j] = (ushort)((ul + 0x7FFF + ((ul >> 16) & 1)) >> 16);
        } else {
            o[j] = (ushort)hi;
        }
    }
    ushort* dst = (isA ? Ap : Bp) + (long)f * 8;
    *(uint4*)dst = *(const uint4*)o;
}

// ---------------- stage 1: MFMA GEMM, tile 128x64, 4 waves 2x2, BK=64 dbuf ----------------
// Epilogue stores exp panels: E1[(b*8+ti)*512+o]*32+ii] = exp2(SCALE*(p1+bias)), E2 likewise.
__global__ __launch_bounds__(256) void mfma_gemm(const ushort* __restrict__ Ap,
                                                 const ushort* __restrict__ Bp,
                                                 const float* __restrict__ attn_b,
                                                 float* __restrict__ E1,
                                                 float* __restrict__ E2) {
    const int mb = blockIdx.x & 15;   // 16 m-tiles of 128
    const int nb = blockIdx.x >> 4;   // 16 n-tiles of 64
    __shared__ ushort lds[2][12288];  // per buf: A half0 4096 | A half1 4096 | B 4096

    const int t = threadIdx.x;
    const int lane = t & 63, w = t >> 6;
    const int wr = w >> 1, wc = w & 1;          // wave-tile 64(m) x 32(n)

    const ushort* A0 = Ap + (long)(mb * 2 + 0) * 24 * 4096;
    const ushort* A1 = Ap + (long)(mb * 2 + 1) * 24 * 4096;
    const ushort* B0 = Bp + (long)nb * 24 * 4096;

    f32x4 acc[4][2];
#pragma unroll
    for (int i = 0; i < 4; ++i)
#pragma unroll
        for (int j = 0; j < 2; ++j)
            acc[i][j] = (f32x4){0.f, 0.f, 0.f, 0.f};

    uint4 st[6];
    // prologue: stage kt=0
    st[0] = ((const uint4*)A0)[t];       st[1] = ((const uint4*)A0)[t + 256];
    st[2] = ((const uint4*)A1)[t];       st[3] = ((const uint4*)A1)[t + 256];
    st[4] = ((const uint4*)B0)[t];       st[5] = ((const uint4*)B0)[t + 256];
#pragma unroll
    for (int r = 0; r < 6; ++r) ((uint4*)lds[0])[t + r * 256] = st[r];
    __syncthreads();

    for (int kt = 0; kt < 24; ++kt) {
        if (kt < 23) {
            const uint4* a0 = (const uint4*)(A0 + (kt + 1) * 4096);
            const uint4* a1 = (const uint4*)(A1 + (kt + 1) * 4096);
            const uint4* b0 = (const uint4*)(B0 + (kt + 1) * 4096);
            st[0] = a0[t]; st[1] = a0[t + 256];
            st[2] = a1[t]; st[3] = a1[t + 256];
            st[4] = b0[t]; st[5] = b0[t + 256];
        }
        const ushort* buf = lds[kt & 1];
#pragma unroll
        for (int ks = 0; ks < 2; ++ks) {
            bf16x8 a[4], b[2];
#pragma unroll
            for (int mf = 0; mf < 4; ++mf)
                a[mf] = *(const bf16x8*)&buf[wr * 4096 + ks * 2048 + mf * 512 + lane * 8];
#pragma unroll
            for (int nn = 0; nn < 2; ++nn)
                b[nn] = *(const bf16x8*)&buf[8192 + ks * 2048 + (wc * 2 + nn) * 512 + lane * 8];
#pragma unroll
            for (int mf = 0; mf < 4; ++mf)
#pragma unroll
                for (int nn = 0; nn < 2; ++nn)
                    acc[mf][nn] = __builtin_amdgcn_mfma_f32_16x16x32_bf16(
                        a[mf], b[nn], acc[mf][nn], 0, 0, 0);
        }
        if (kt < 23) {
            ushort* nbuf = lds[(kt + 1) & 1];
#pragma unroll
            for (int r = 0; r < 6; ++r) ((uint4*)nbuf)[t + r * 256] = st[r];
            __syncthreads();
        }
    }

    // epilogue: C row = mb*128 + wr*64 + mf*16 + (lane>>4)*4 + r ; col = nb*64 + wc*32 + nf*16 + (lane&15)
    const bool isE1 = (nb < 8);
    float* dst = isE1 ? E1 : E2;
    const int b = mb >> 1;
#pragma unroll
    for (int nn = 0; nn < 2; ++nn) {
        int n = nb * 64 + wc * 32 + nn * 16 + (lane & 15);
        int o = n & 511;
        float bias = isE1 ? attn_b[o] : 0.0f;
#pragma unroll
        for (int mf = 0; mf < 4; ++mf) {
            int ti = (mb & 1) * 4 + wr * 2 + (mf >> 1);
            int iibase = (mf & 1) * 16 + (lane >> 4) * 4;
            long rowoff = ((long)(b * 8 + ti) * 512 + o) * 32 + iibase;
#pragma unroll
            for (int r = 0; r < 4; ++r)
                dst[rowoff + r] = fast_exp2(SCALE * (acc[mf][nn][r] + bias));
        }
    }
}

// ---------------- stage 2: partial energies ----------------
// EP[s][b][i][j] = sum_{o in chunk s} c[o] * rcp(1 + E1[b,i,o]*E2[b,j,o]),  c[o]=2*score_W[o]
__global__ __launch_bounds__(256) void energy_kernel(const float* __restrict__ E1,
                                                     const float* __restrict__ E2,
                                                     const float* __restrict__ sW,
                                                     float* __restrict__ EP) {
    const int bid = blockIdx.x;       // 2048 = 8 b * 8 ti * 8 tj * 4 s
    const int s  = bid & 3;
    const int tj = (bid >> 2) & 7;
    const int ti = (bid >> 5) & 7;
    const int b  = bid >> 8;
    __shared__ float p1s[64 * 32];
    __shared__ float p2s[64 * 32];
    __shared__ float csh[128];

    const int t = threadIdx.x;
    const int tx = t & 15, ty = t >> 4;

    if (t < 128) csh[t] = 2.0f * sW[s * 128 + t];

    const float* p1base = E1 + ((long)(b * 8 + ti) * 512 + s * 128) * 32;
    const float* p2base = E2 + ((long)(b * 8 + tj) * 512 + s * 128) * 32;

    float acc00 = 0.f, acc01 = 0.f, acc10 = 0.f, acc11 = 0.f;

    for (int c0 = 0; c0 < 128; c0 += 64) {
        __syncthreads();
        const float4* s1 = (const float4*)(p1base + c0 * 32);
        const float4* s2 = (const float4*)(p2base + c0 * 32);
        float4* d1 = (float4*)p1s;
        float4* d2 = (float4*)p2s;
        d1[t] = s1[t];  d1[256 + t] = s1[256 + t];
        d2[t] = s2[t];  d2[256 + t] = s2[256 + t];
        __syncthreads();
#pragma unroll 8
        for (int hh = 0; hh < 64; ++hh) {
            float c = csh[c0 + hh];
            float2 a  = *(const float2*)&p1s[hh * 32 + ty * 2];
            float2 bj = *(const float2*)&p2s[hh * 32 + tx * 2];
            acc00 = fmaf(c, fast_rcp(fmaf(a.x, bj.x, 1.0f)), acc00);
            acc01 = fmaf(c, fast_rcp(fmaf(a.x, bj.y, 1.0f)), acc01);
            acc10 = fmaf(c, fast_rcp(fmaf(a.y, bj.x, 1.0f)), acc10);
            acc11 = fmaf(c, fast_rcp(fmaf(a.y, bj.y, 1.0f)), acc11);
        }
    }

    float* Eb = EP + (long)s * 524288 + (long)b * 65536 + (ti * 32) * 256 + tj * 32;
    *(float2*)&Eb[(ty * 2 + 0) * 256 + tx * 2] = make_float2(acc00, acc01);
    *(float2*)&Eb[(ty * 2 + 1) * 256 + tx * 2] = make_float2(acc10, acc11);
}

// ---------------- stage 3: combine partials + softmax over i (axis=1) ----------------
__global__ __launch_bounds__(256) void softmax_kernel(const float* __restrict__ P0,
                                                      const float* __restrict__ P1,
                                                      const float* __restrict__ P2,
                                                      const float* __restrict__ P3,
                                                      float* __restrict__ out) {
    const int b  = blockIdx.x >> 4;
    const int jt = blockIdx.x & 15;
    const int t  = threadIdx.x;
    const int jx = t & 15;
    const int iy = t >> 4;
    const long base = (long)b * 65536 + jt * 16 + jx;

    float v[16];
#pragma unroll
    for (int k = 0; k < 16; ++k) {
        long idx = base + (long)(iy + k * 16) * 256;
        v[k] = -(P0[idx] + P1[idx] + P2[idx] + P3[idx]);
    }

    float m = v[0];
#pragma unroll
    for (int k = 1; k < 16; ++k) m = fmaxf(m, v[k]);

    __shared__ float red[256];
    red[t] = m;
    __syncthreads();
    if (t < 128) red[t] = fmaxf(red[t], red[t + 128]);
    __syncthreads();
    if (t < 64) red[t] = fmaxf(red[t], red[t + 64]);
    __syncthreads();
    if (t < 32) red[t] = fmaxf(red[t], red[t + 32]);
    __syncthreads();
    if (t < 16) red[t] = fmaxf(red[t], red[t + 16]);
    __syncthreads();
    m = red[jx];
    __syncthreads();

    float ssum = 0.f;
#pragma unroll
    for (int k = 0; k < 16; ++k) {
        v[k] = fast_exp2((v[k] - m) * LOG2E);
        ssum += v[k];
    }
    red[t] = ssum;
    __syncthreads();
    if (t < 128) red[t] += red[t + 128];
    __syncthreads();
    if (t < 64) red[t] += red[t + 64];
    __syncthreads();
    if (t < 32) red[t] += red[t + 32];
    __syncthreads();
    if (t < 16) red[t] += red[t + 16];
    __syncthreads();
    float inv = fast_rcp(red[jx]);

#pragma unroll
    for (int k = 0; k < 16; ++k) {
        long idx = base + (long)(iy + k * 16) * 256;
        out[idx] = v[k] * inv;
    }
}

extern "C" void kernel_launch(void* const* d_in, const int* in_sizes, int n_in,
                              void* d_out, int out_size, void* d_ws, size_t ws_size,
                              hipStream_t stream) {
    const float* inputs  = (const float*)d_in[0];  // (256, 8, 512)
    const float* attn_W  = (const float*)d_in[1];  // (512, 1024)
    const float* attn_b  = (const float*)d_in[2];  // (512,)
    const float* score_W = (const float*)d_in[3];  // (1, 512)
    float* out = (float*)d_out;                    // (8, 256, 256)

    float* ws = (float*)d_ws;
    float* E1 = ws;                                // 1M f32 exp panel (4 MB)
    float* E2 = ws + (1 << 20);                    // 1M f32 (4 MB)
    float* EP = ws + (2 << 20);                    // 4 * 512K f32 partials (8 MB)
    ushort* Ap = (ushort*)(ws + (4 << 20));        // 3.146M bf16 (6.3 MB)
    ushort* Bp = Ap + 3145728;                     // 1.573M bf16 (3.2 MB)

    pack_kernel<<<2304, 256, 0, stream>>>(inputs, attn_W, Ap, Bp);
    mfma_gemm<<<256, 256, 0, stream>>>(Ap, Bp, attn_b, E1, E2);
    energy_kernel<<<2048, 256, 0, stream>>>(E1, E2, score_W, EP);
    softmax_kernel<<<128, 256, 0, stream>>>(EP, EP + 524288, EP + 2 * 524288,
                                            EP + 3 * 524288, out);
}